// Round 8
// baseline (955.467 us; speedup 1.0000x reference)
//
#include <hip/hip_runtime.h>
#include <stdint.h>

#define TSTEPS 1000
#define NB 256
#define NF 64
#define NH 256   // H1 == H2 == 256
#define CHUNK 8
#define NCH 125  // 125 * 8 == 1000, no tail

// Prep: transpose W2 (H2,H1) -> W2T[h1][h2] in d_ws for coalesced gathers,
// and zero the two global spike counters.
__global__ void snn_prep(const float* __restrict__ W2, float* __restrict__ W2T,
                         unsigned int* __restrict__ counts) {
    int idx = blockIdx.x * 256 + threadIdx.x;     // idx = h1*256 + h2
    W2T[idx] = W2[(idx & 255) * 256 + (idx >> 8)];
    if (idx < 2) counts[idx] = 0u;
}

// Producer step: sparse ctz gather from LDS W1T (round-0-proven form).
// The ballot mask is WAVE-UNIFORM -> every iteration all 64 lanes read the
// same row f at consecutive h: stride-1, 2 lanes/bank, zero conflicts, and
// f lives in an SGPR (s_ff1) -> no per-lane address math. ~13 active
// features/step at 20% firing = ~4 iterations of 4 chains.
// Summation order: ascending f within each 16-feature quarter, then
// (a0+a1)+(a2+a3) — bit-exact match to all previous passing rounds.
#define PSTEP(pb, tt, xv) do {                                                \
    unsigned long long xm = __ballot((xv) > 0.f);                             \
    unsigned xm0 = (unsigned)(xm & 0xFFFFull);                                \
    unsigned xm1 = (unsigned)((xm >> 16) & 0xFFFFull);                        \
    unsigned xm2 = (unsigned)((xm >> 32) & 0xFFFFull);                        \
    unsigned xm3 = (unsigned)((xm >> 48) & 0xFFFFull);                        \
    float a0 = 0.f, a1 = 0.f, a2 = 0.f, a3 = 0.f;                             \
    while (xm0 | xm1 | xm2 | xm3) {                                           \
        if (xm0) { int f = __builtin_ctz(xm0); xm0 &= xm0 - 1; a0 += W1T[f][h]; }      \
        if (xm1) { int f = __builtin_ctz(xm1); xm1 &= xm1 - 1; a1 += W1T[f + 16][h]; } \
        if (xm2) { int f = __builtin_ctz(xm2); xm2 &= xm2 - 1; a2 += W1T[f + 32][h]; } \
        if (xm3) { int f = __builtin_ctz(xm3); xm3 &= xm3 - 1; a3 += W1T[f + 48][h]; } \
    }                                                                         \
    float cur1 = b1h + ((a0 + a1) + (a2 + a3));                               \
    float reset1 = (mem1 > 1.f) ? 1.f : 0.f;                                  \
    mem1 = 0.8187307530779818f * mem1 + cur1 - reset1; /* beta1=exp(-1/5) */  \
    bool s1 = (mem1 - 1.f) > 0.f;                                             \
    cnt1 += (int)s1;                                                          \
    unsigned long long sm = __ballot(s1);                                     \
    if (lane == 0) scnt8[pb][(tt) * 4 + wv] = (unsigned char)__popcll(sm);    \
    if (s1) {                                                                 \
        int rank = __popcll(sm & ((1ull << lane) - 1ull));                    \
        slist[pb][tt][(wv << 6) + rank] = (unsigned char)h;                   \
    }                                                                         \
} while (0)

// Consumer step: read the 5 metadata words (named locals), branch-free
// first-4 gather with value masking (order matches the guarded loop
// exactly), rare overflow path, mem2 update.
#define CSTEP(cb, tt) do {                                                    \
    unsigned int cwv = *(const unsigned int*)&scnt8[cb][(tt) * 4];            \
    unsigned int u0 = *(const unsigned int*)&slist[cb][tt][0];                \
    unsigned int u1 = *(const unsigned int*)&slist[cb][tt][64];               \
    unsigned int u2 = *(const unsigned int*)&slist[cb][tt][128];              \
    unsigned int u3 = *(const unsigned int*)&slist[cb][tt][192];              \
    int c0 = (int)(cwv & 255u),        c1 = (int)((cwv >> 8) & 255u);         \
    int c2 = (int)((cwv >> 16) & 255u), c3 = (int)((cwv >> 24) & 255u);       \
    float q0 = 0.f, q1 = 0.f, q2 = 0.f, q3 = 0.f;                             \
    _Pragma("unroll")                                                         \
    for (int i = 0; i < 4; ++i) {                                             \
        float v0 = W2Th[(int)((u0 >> (8 * i)) & 255u) << 8];                  \
        float v1 = W2Th[(int)((u1 >> (8 * i)) & 255u) << 8];                  \
        float v2 = W2Th[(int)((u2 >> (8 * i)) & 255u) << 8];                  \
        float v3 = W2Th[(int)((u3 >> (8 * i)) & 255u) << 8];                  \
        q0 += (i < c0) ? v0 : 0.f;                                            \
        q1 += (i < c1) ? v1 : 0.f;                                            \
        q2 += (i < c2) ? v2 : 0.f;                                            \
        q3 += (i < c3) ? v3 : 0.f;                                            \
    }                                                                         \
    int nmax = max(max(c0, c1), max(c2, c3));                                 \
    if (nmax > 4) {   /* rare overflow path (per-wave spike count > 4) */     \
        const unsigned char* sl = &slist[cb][tt][0];                          \
        for (int i = 4; i < nmax; ++i) {                                      \
            if (i < c0) q0 += W2Th[(int)sl[i] << 8];                          \
            if (i < c1) q1 += W2Th[(int)sl[64 + i] << 8];                     \
            if (i < c2) q2 += W2Th[(int)sl[128 + i] << 8];                    \
            if (i < c3) q3 += W2Th[(int)sl[192 + i] << 8];                    \
        }                                                                     \
    }                                                                         \
    float cur2 = b2h + ((q0 + q1) + (q2 + q3));                               \
    float reset2 = (mem2 > 1.f) ? 1.f : 0.f;                                  \
    mem2 = 0.9048374180359595f * mem2 + cur2 - reset2; /* beta2=exp(-1/10) */ \
    bool s2 = (mem2 - 1.f) > 0.f;                                             \
    cnt2 += (int)s2;                                                          \
    mem2s += mem2;                                                            \
} while (0)

// Main: one 512-thread workgroup per batch, wave-specialized pipeline.
//   waves 0-3 (producer): own mem1[h], layer 1 for chunk c -> slist[c&1].
//   waves 4-7 (consumer): own mem2[h], layer 2 for chunk c-1.
// Layer-1 weights live in LDS (W1T), NOT per-thread registers — rounds 1-7
// proved (VGPR stuck at 68-88) that the compiler always rematerializes
// per-thread W1 copies as in-loop reloads; LDS + wave-uniform sparse gather
// sidesteps that entirely.
__launch_bounds__(512, 2)
__global__ void snn_main(const float* __restrict__ spikes,
                         const float* __restrict__ W1,
                         const float* __restrict__ b1,
                         const float* __restrict__ W2T,
                         const float* __restrict__ b2,
                         const float* __restrict__ Wr,
                         const float* __restrict__ br,
                         float* __restrict__ out,
                         unsigned int* __restrict__ counts) {
    const int b = blockIdx.x;
    const int tid = threadIdx.x;
    const int lane = tid & 63;
    const int wv = tid >> 6;          // 0..7
    const bool producer = (wv < 4);
    const int h = tid & 255;          // hidden index within the role group

    __shared__ float W1T[NF][NH + 1];              // +1 pad: staging writes conflict-free
    __shared__ unsigned char slist[2][CHUNK][256]; // per-chunk-buf spk1 lists
    __shared__ unsigned char scnt8[2][CHUNK * 4];  // per-step per-wave counts
    __shared__ float rp0[4], rp1[4];
    __shared__ int rc1[4], rc2[4];

    const size_t xstride = (size_t)NB * NF;
    const float* xbase = spikes + (size_t)b * NF + lane;  // per-lane x ptr
    const float* W2Th = W2T + h;

    // Cooperative staging: W1T[f][h1] = W1[h1*64+f]. Coalesced global reads;
    // LDS write banks (f + h) % 32 vary with f -> conflict-free.
    for (int i = tid; i < NH * NF; i += 512) {
        W1T[i & 63][i >> 6] = W1[i];
    }

    float mem1 = 0.f, mem2 = 0.f, mem2s = 0.f;
    int cnt1 = 0, cnt2 = 0;
    float b1h = 0.f, b2h = 0.f;
    float xq0 = 0.f, xq1 = 0.f, xq2 = 0.f, xq3 = 0.f;
    float xq4 = 0.f, xq5 = 0.f, xq6 = 0.f, xq7 = 0.f;

    if (producer) {
        b1h = b1[h];
        // chunk-0 inputs: per-lane x[t][b][lane]; 64 lanes -> 256B coalesced
        xq0 = xbase[0];
        xq1 = xbase[xstride];
        xq2 = xbase[2 * xstride];
        xq3 = xbase[3 * xstride];
        xq4 = xbase[4 * xstride];
        xq5 = xbase[5 * xstride];
        xq6 = xbase[6 * xstride];
        xq7 = xbase[7 * xstride];
    } else {
        b2h = b2[h];
    }
    __syncthreads();   // W1T staged and visible to producer waves

    for (int c = 0; c < NCH; ++c) {
        if (producer) {
            const int pb = c & 1;
            // ---- layer 1: CHUNK steps, LDS-only gathers ----
            PSTEP(pb, 0, xq0); PSTEP(pb, 1, xq1);
            PSTEP(pb, 2, xq2); PSTEP(pb, 3, xq3);
            PSTEP(pb, 4, xq4); PSTEP(pb, 5, xq5);
            PSTEP(pb, 6, xq6); PSTEP(pb, 7, xq7);
            // prefetch next chunk's inputs; consumed after the barrier ->
            // latency hidden under the paired consumer wave's work.
            int cn = (c + 1 < NCH) ? c + 1 : 0;  // clamped dummy on last
            const float* xb = xbase + (size_t)cn * CHUNK * xstride;
            xq0 = xb[0];
            xq1 = xb[xstride];
            xq2 = xb[2 * xstride];
            xq3 = xb[3 * xstride];
            xq4 = xb[4 * xstride];
            xq5 = xb[5 * xstride];
            xq6 = xb[6 * xstride];
            xq7 = xb[7 * xstride];
        } else if (c > 0) {
            const int cb = (c - 1) & 1;
            // ---- layer 2: CHUNK steps for chunk c-1 ----
            CSTEP(cb, 0); CSTEP(cb, 1); CSTEP(cb, 2); CSTEP(cb, 3);
            CSTEP(cb, 4); CSTEP(cb, 5); CSTEP(cb, 6); CSTEP(cb, 7);
        }
        __syncthreads();   // chunk handoff: slist[pb] ready; buffers swap
    }
    // pipeline epilogue: last chunk's layer 2
    if (!producer) {
        const int cb = (NCH - 1) & 1;
        CSTEP(cb, 0); CSTEP(cb, 1); CSTEP(cb, 2); CSTEP(cb, 3);
        CSTEP(cb, 4); CSTEP(cb, 5); CSTEP(cb, 6); CSTEP(cb, 7);
    }

    // readout: out[b,:] = (mem2_sum/T) @ Wr.T + br ; role-local reductions
    if (producer) {
        int rcs1 = cnt1;
        for (int off = 32; off > 0; off >>= 1) rcs1 += __shfl_down(rcs1, off);
        if (lane == 0) rc1[wv] = rcs1;
    } else {
        float v = mem2s / 1000.0f;
        float p0 = v * Wr[h];
        float p1 = v * Wr[NH + h];
        int rcs2 = cnt2;
        for (int off = 32; off > 0; off >>= 1) {
            p0 += __shfl_down(p0, off);
            p1 += __shfl_down(p1, off);
            rcs2 += __shfl_down(rcs2, off);
        }
        if (lane == 0) { rp0[wv - 4] = p0; rp1[wv - 4] = p1; rc2[wv - 4] = rcs2; }
    }
    __syncthreads();
    if (tid == 0) {
        out[2 * b]     = ((rp0[0] + rp0[1]) + (rp0[2] + rp0[3])) + br[0];
        out[2 * b + 1] = ((rp1[0] + rp1[1]) + (rp1[2] + rp1[3])) + br[1];
        atomicAdd(&counts[0], (unsigned)(rc1[0] + rc1[1] + rc1[2] + rc1[3]));
        atomicAdd(&counts[1], (unsigned)(rc2[0] + rc2[1] + rc2[2] + rc2[3]));
    }
}

__global__ void snn_finalize(const unsigned int* __restrict__ counts,
                             float* __restrict__ out) {
    if (threadIdx.x < 2)
        out[512 + threadIdx.x] = (float)counts[threadIdx.x] / 65536000.0f; // T*B*256
}

extern "C" void kernel_launch(void* const* d_in, const int* in_sizes, int n_in,
                              void* d_out, int out_size, void* d_ws, size_t ws_size,
                              hipStream_t stream) {
    const float* spikes = (const float*)d_in[0];
    const float* W1     = (const float*)d_in[1];
    const float* b1     = (const float*)d_in[2];
    const float* W2     = (const float*)d_in[3];
    const float* b2     = (const float*)d_in[4];
    const float* Wr     = (const float*)d_in[5];
    const float* br     = (const float*)d_in[6];
    float* out = (float*)d_out;

    float* W2T = (float*)d_ws;                                   // 256 KB
    unsigned int* counts = (unsigned int*)((char*)d_ws + (size_t)NH * NH * sizeof(float));

    snn_prep<<<256, 256, 0, stream>>>(W2, W2T, counts);
    snn_main<<<256, 512, 0, stream>>>(spikes, W1, b1, W2T, b2, Wr, br, out, counts);
    snn_finalize<<<1, 64, 0, stream>>>(counts, out);
}